// Round 1
// 1287.477 us; speedup vs baseline: 1.0019x; 1.0019x over previous
//
#include <hip/hip_runtime.h>

// ---------------------------------------------------------------------------
// Segment-mean (MeanAggregator): out[m, :] = mean over atoms of molecule m.
// segment_ids are sorted; every molecule has >= 1 atom.
//
// Memory-bound: ~1.03 GB read + ~52 MB write -> roofline ~172 us @ 6.3 TB/s.
// Measured total (~1290 us) is dominated by harness workspace re-poison
// fills (2 x 4.096 GB fillBufferAligned @ ~650 us each, per rocprof).
//
// This version:
//  - single fused kernel (no seg_starts dispatch, no workspace use, no
//    inter-kernel graph dependency)
//  - boundary resolution via verified uniform-layout guess: 4 independent
//    broadcast probes of segment_ids instead of a 42-probe dependent
//    binary-search chain; exact for arbitrary inputs (per-thread bsearch
//    fallback if any probe fails)
//  - cols4==32 specialized as a compile-time constant (div -> shift)
// ---------------------------------------------------------------------------

__device__ __forceinline__ float4 f4add(float4 a, float4 b) {
    return make_float4(a.x + b.x, a.y + b.y, a.z + b.z, a.w + b.w);
}

__device__ __forceinline__ int lower_bound_dev(const int* __restrict__ seg,
                                               int n, int val) {
    int lo = 0, hi = n;
    while (lo < hi) {
        int mid = (lo + hi) >> 1;
        if (seg[mid] < val) lo = mid + 1; else hi = mid;
    }
    return lo;
}

// One thread per output float4. Lanes 0..31 of a wave handle the 32 column
// float4s of molecule M, lanes 32..63 handle molecule M+1 -> every wave load
// is two contiguous 512 B rows, fully coalesced.
//
// app > 0: candidate uniform atoms-per-molecule (n_atoms / n_mols when it
// divides evenly). Each thread verifies the uniform guess for ITS molecule
// with 4 independent loads (all broadcast across its 32-lane group, seg is
// L2-resident). Verification is exact:
//   seg sorted, seg[s]==m and seg[s-1]!=m  => start(m)==s
//   seg sorted, seg[e-1]==m and seg[e]!=m  => end(m)==e
// If any check fails (non-uniform input), fall back to binary search.
template <int COLS4>
__global__ __launch_bounds__(256)
void seg_mean_fused(const float4* __restrict__ a4,
                    const int* __restrict__ seg,
                    float4* __restrict__ out4,
                    int cols4_rt, int app, int n_atoms, long long n_out4) {
    long long idx = (long long)blockIdx.x * blockDim.x + threadIdx.x;
    if (idx >= n_out4) return;

    const int cols4 = (COLS4 > 0) ? COLS4 : cols4_rt;
    int mol, col;
    if (COLS4 == 32) {
        mol = (int)(idx >> 5);
        col = (int)(idx & 31);
    } else {
        mol = (int)(idx / cols4);
        col = (int)(idx - (long long)mol * cols4);
    }

    int start, end;
    bool resolved = false;
    if (app > 0) {
        int s = mol * app;
        int e = s + app;
        // 4 independent probes -> single memory round-trip, broadcast
        // within each 32-lane group.
        int v0 = seg[s];
        int v1 = seg[e - 1];
        int vp = (s == 0)       ? (mol - 1) : seg[s - 1];
        int vn = (e == n_atoms) ? (mol + 1) : seg[e];
        if (v0 == mol && v1 == mol && vp != mol && vn != mol) {
            start = s;
            end   = e;
            resolved = true;
        }
    }
    if (!resolved) {
        start = lower_bound_dev(seg, n_atoms, mol);
        end   = lower_bound_dev(seg, n_atoms, mol + 1);
    }
    int cnt = end - start;   // >= 1 guaranteed

    const float4* p = a4 + (long long)start * cols4 + col;
    float4 acc = make_float4(0.f, 0.f, 0.f, 0.f);

    int r = 0;
    for (; r + 4 <= cnt; r += 4) {   // 4 loads in flight per thread
        float4 a = p[(long long)(r + 0) * cols4];
        float4 b = p[(long long)(r + 1) * cols4];
        float4 c = p[(long long)(r + 2) * cols4];
        float4 d = p[(long long)(r + 3) * cols4];
        acc = f4add(acc, f4add(f4add(a, b), f4add(c, d)));
    }
    for (; r < cnt; ++r) {
        acc = f4add(acc, p[(long long)r * cols4]);
    }

    float fc = (float)cnt;
    acc.x /= fc;
    acc.y /= fc;
    acc.z /= fc;
    acc.w /= fc;

    out4[idx] = acc;
}

extern "C" void kernel_launch(void* const* d_in, const int* in_sizes, int n_in,
                              void* d_out, int out_size, void* d_ws, size_t ws_size,
                              hipStream_t stream) {
    const float* atom_hiddens = (const float*)d_in[0];
    const int*   segment_ids  = (const int*)d_in[1];
    // d_in[2] is n_mols on device; derive everything host-side from sizes
    // (graph-capture safe, no readback). Sizes are element counts.
    int n_atoms = in_sizes[1];
    int hidden  = in_sizes[0] / n_atoms;   // 128
    int n_mols  = out_size / hidden;       // 100000
    int cols4   = hidden / 4;              // 32

    // Uniform-layout candidate: exact division => likely fixed atoms/mol.
    // Device code verifies per molecule, so this is safe for any input.
    int app = (n_mols > 0 && n_atoms % n_mols == 0) ? (n_atoms / n_mols) : 0;

    long long n_out4 = (long long)n_mols * cols4;
    int blk = 256;
    int grid = (int)((n_out4 + blk - 1) / blk);

    (void)d_ws; (void)ws_size; (void)n_in;

    if (cols4 == 32) {
        seg_mean_fused<32><<<grid, blk, 0, stream>>>(
            (const float4*)atom_hiddens, segment_ids, (float4*)d_out,
            cols4, app, n_atoms, n_out4);
    } else {
        seg_mean_fused<0><<<grid, blk, 0, stream>>>(
            (const float4*)atom_hiddens, segment_ids, (float4*)d_out,
            cols4, app, n_atoms, n_out4);
    }
}